// Round 1
// baseline (2592.953 us; speedup 1.0000x reference)
//
#include <hip/hip_runtime.h>
#include <hip/hip_bf16.h>
#include <cstdint>

// ---------------------------------------------------------------------------
// Types / helpers
// ---------------------------------------------------------------------------
typedef __bf16 bf16_t;
typedef __attribute__((ext_vector_type(8))) __bf16 bf16x8;
typedef __attribute__((ext_vector_type(4))) float f32x4;

__device__ __forceinline__ float b2f(ushort u) {
    union { float f; uint32_t i; } x; x.i = ((uint32_t)u) << 16; return x.f;
}
__device__ __forceinline__ ushort f2b(float f) {
    uint32_t i = __builtin_bit_cast(uint32_t, f);
    uint32_t r = (i + 0x7FFFu + ((i >> 16) & 1u)) >> 16;   // RNE
    return (ushort)r;
}

// async global->LDS, 16 bytes per lane; lds ptr must be wave-uniform base
__device__ __forceinline__ void g2l16(const ushort* gp, ushort* lp) {
    __builtin_amdgcn_global_load_lds(
        (const __attribute__((address_space(1))) uint32_t*)gp,
        (__attribute__((address_space(3))) uint32_t*)lp, 16, 0, 0);
}

// ---------------------------------------------------------------------------
// LN1 + pack x into GEMM-A layout: A1[patch=(b*32+gh)*32+gw][(i*8+j)*32+c] bf16
// ---------------------------------------------------------------------------
__global__ __launch_bounds__(256) void ln1_pack(
    const float* __restrict__ x, const float* __restrict__ g,
    const float* __restrict__ b, ushort* __restrict__ A1) {
    int pix = blockIdx.x * 256 + threadIdx.x;      // 0..131071
    const float4* xp = (const float4*)(x + (size_t)pix * 32);
    float v[32]; float s = 0.f;
#pragma unroll
    for (int i = 0; i < 8; ++i) {
        float4 f = xp[i];
        v[i*4+0] = f.x; v[i*4+1] = f.y; v[i*4+2] = f.z; v[i*4+3] = f.w;
        s += f.x + f.y + f.z + f.w;
    }
    float mu = s * (1.f/32.f), s2 = 0.f;
#pragma unroll
    for (int i = 0; i < 32; ++i) { float d = v[i]-mu; s2 += d*d; }
    float inv = rsqrtf(s2 * (1.f/32.f) + 1e-6f);
    int w = pix & 255, h = (pix >> 8) & 255, bb = pix >> 16;
    size_t row = ((size_t)bb*32 + (h>>3))*32 + (w>>3);
    ushort* dst = A1 + row*2048 + (size_t)((h&7)*8 + (w&7))*32;
    ushort o[32];
#pragma unroll
    for (int i = 0; i < 32; ++i) o[i] = f2b((v[i]-mu)*inv*g[i] + b[i]);
    uint4* d4 = (uint4*)dst; const uint4* s4 = (const uint4*)o;
#pragma unroll
    for (int i = 0; i < 4; ++i) d4[i] = s4[i];
}

// ---------------------------------------------------------------------------
// Weight fp32 [K,N] (n-contig) -> bf16 [N,K] (k-contig) transpose+convert
// ---------------------------------------------------------------------------
__global__ __launch_bounds__(256) void wcvt(
    const float* __restrict__ W, ushort* __restrict__ WT, int K, int N) {
    __shared__ float tile[64][65];
    int n0 = blockIdx.x * 64, k0 = blockIdx.y * 64;
    int t = threadIdx.x;
    int col4 = (t & 15) * 4, krow = t >> 4;
#pragma unroll
    for (int it = 0; it < 4; ++it) {
        int kk = it*16 + krow;
        float4 f = *(const float4*)(W + (size_t)(k0+kk)*N + n0 + col4);
        tile[kk][col4+0] = f.x; tile[kk][col4+1] = f.y;
        tile[kk][col4+2] = f.z; tile[kk][col4+3] = f.w;
    }
    __syncthreads();
    int n = t >> 2, ch = t & 3;
    ushort o[16];
#pragma unroll
    for (int i = 0; i < 16; ++i) o[i] = f2b(tile[ch*16 + i][n]);
    uint4* dst = (uint4*)(WT + (size_t)(n0+n)*K + k0 + ch*16);
    dst[0] = ((const uint4*)o)[0];
    dst[1] = ((const uint4*)o)[1];
}

// ---------------------------------------------------------------------------
// bf16 MFMA GEMM: C[M,N] = A[M,K] * Bt[N,K]^T, 128x128 tile, BK=32
// EPI=0: C = acc + bias[n] -> bf16 Cb ;  EPI=1: atomicAdd remapped into Out
// ---------------------------------------------------------------------------
template <int EPI>
__global__ __launch_bounds__(256, 2) void gemm_bt(
    const ushort* __restrict__ A, const ushort* __restrict__ Bt,
    const float* __restrict__ bias, ushort* __restrict__ Cb,
    float* __restrict__ Out, int M, int N, int K, int KS) {
    __shared__ __align__(16) ushort sA[128*32];
    __shared__ __align__(16) ushort sB[128*32];
    const int tid = threadIdx.x;
    const int wave = tid >> 6, lane = tid & 63;
    const int lrow = lane & 15, lquad = lane >> 4;
    const int m0 = blockIdx.y * 128, n0 = blockIdx.x * 128;
    const int wm = (wave & 1) * 64, wn = (wave >> 1) * 64;

    // staging map: chunk ci -> LDS pos (r, q'); global kquad = q' ^ ((r>>1)&3)
    const int r0 = tid >> 2,        q0 = (tid & 3) ^ ((r0 >> 1) & 3);
    const int r1 = (256+tid) >> 2,  q1 = (tid & 3) ^ ((r1 >> 1) & 3);
    ushort* lA0 = sA + wave*512;          ushort* lA1 = sA + 2048 + wave*512;
    ushort* lB0 = sB + wave*512;          ushort* lB1 = sB + 2048 + wave*512;
    const size_t aRow0 = (size_t)(m0 + r0) * K, aRow1 = (size_t)(m0 + r1) * K;
    const size_t bRow0 = (size_t)(n0 + r0) * K, bRow1 = (size_t)(n0 + r1) * K;

    // fragment LDS addresses (constant per thread)
    const ushort* aAddr[4]; const ushort* bAddr[4];
#pragma unroll
    for (int i = 0; i < 4; ++i) {
        int r = wm + i*16 + lrow;
        aAddr[i] = sA + r*32 + ((lquad ^ ((r >> 1) & 3)) * 8);
        int nn = wn + i*16 + lrow;
        bAddr[i] = sB + nn*32 + ((lquad ^ ((nn >> 1) & 3)) * 8);
    }

    f32x4 acc[4][4];
#pragma unroll
    for (int i = 0; i < 4; ++i)
#pragma unroll
        for (int j = 0; j < 4; ++j) acc[i][j] = f32x4{0.f, 0.f, 0.f, 0.f};

    const int kbeg = (EPI == 1) ? blockIdx.z * KS : 0;
    const int kend = kbeg + KS;
    for (int kt = kbeg; kt < kend; kt += 32) {
        __syncthreads();
        g2l16(A  + aRow0 + kt + q0*8, lA0);
        g2l16(A  + aRow1 + kt + q1*8, lA1);
        g2l16(Bt + bRow0 + kt + q0*8, lB0);
        g2l16(Bt + bRow1 + kt + q1*8, lB1);
        __syncthreads();
        bf16x8 af[4], bg[4];
#pragma unroll
        for (int i = 0; i < 4; ++i) {
            af[i] = __builtin_bit_cast(bf16x8, *(const uint4*)aAddr[i]);
            bg[i] = __builtin_bit_cast(bf16x8, *(const uint4*)bAddr[i]);
        }
#pragma unroll
        for (int i = 0; i < 4; ++i)
#pragma unroll
            for (int j = 0; j < 4; ++j)
                acc[i][j] = __builtin_amdgcn_mfma_f32_16x16x32_bf16(
                    af[i], bg[j], acc[i][j], 0, 0, 0);
    }

    if constexpr (EPI == 0) {
#pragma unroll
        for (int j = 0; j < 4; ++j) {
            int n = n0 + wn + j*16 + lrow;
            float bv = bias[n];
#pragma unroll
            for (int i = 0; i < 4; ++i) {
                int mbase = m0 + wm + i*16 + lquad*4;
#pragma unroll
                for (int re = 0; re < 4; ++re)
                    Cb[(size_t)(mbase + re)*N + n] = f2b(acc[i][j][re] + bv);
            }
        }
    } else {
#pragma unroll
        for (int j = 0; j < 4; ++j) {
            int n = n0 + wn + j*16 + lrow;          // f = c*64 + i*8 + j
            int cc = n >> 6, ii = (n >> 3) & 7, jj = n & 7;
#pragma unroll
            for (int i = 0; i < 4; ++i) {
                int mbase = m0 + wm + i*16 + lquad*4;
#pragma unroll
                for (int re = 0; re < 4; ++re) {
                    int mr = mbase + re;            // (b*32+gh)*32+gw
                    int bb = mr >> 10, gh = (mr >> 5) & 31, gw = mr & 31;
                    size_t oi = ((size_t)((bb*256 + gh*8 + ii)*256 + gw*8 + jj))*32 + cc;
                    atomicAdd(Out + oi, acc[i][j][re]);
                }
            }
        }
    }
}

// ---------------------------------------------------------------------------
// Per-patch: 8x8 circular conv (q ⊛ k), LN2 over c, gate by v, pack A2 rows.
// One block per patch; thread t -> (head = t>>5, c = t&31). A2 may alias Qb.
// ---------------------------------------------------------------------------
__global__ __launch_bounds__(256, 2) void conv_gate(
    const ushort* __restrict__ Qb, const ushort* __restrict__ Kb,
    const ushort* __restrict__ Vb, const float* __restrict__ ln2_s,
    const float* __restrict__ ln2_b, ushort* __restrict__ A2) {
    __shared__ __align__(16) ushort sQ[256*72];    // [head*32+c][p], pad 72
    __shared__ __align__(16) ushort sK[256*72];
    const int t = threadIdx.x;
    const int m = blockIdx.x;
    const int c = t & 31;
    const ushort* Qrow = Qb + (size_t)m * 16384;
    const ushort* Krow = Kb + (size_t)m * 16384;
    const ushort* Vrow = Vb + (size_t)m * 16384;

    // stage Q,K: global element (c*512 + p*8 + head) -> sQ[(head*32+c)*72 + p]
#pragma unroll
    for (int it = 0; it < 8; ++it) {
        int ci = it*256 + t;
        int cc = ci >> 6, p = ci & 63;
        uint4 wq = ((const uint4*)Qrow)[ci];
        uint4 wk = ((const uint4*)Krow)[ci];
        uint uq[4] = {wq.x, wq.y, wq.z, wq.w};
        uint uk[4] = {wk.x, wk.y, wk.z, wk.w};
#pragma unroll
        for (int e = 0; e < 4; ++e) {
            sQ[((2*e  )*32 + cc)*72 + p] = (ushort)(uq[e] & 0xffffu);
            sQ[((2*e+1)*32 + cc)*72 + p] = (ushort)(uq[e] >> 16);
            sK[((2*e  )*32 + cc)*72 + p] = (ushort)(uk[e] & 0xffffu);
            sK[((2*e+1)*32 + cc)*72 + p] = (ushort)(uk[e] >> 16);
        }
    }
    __syncthreads();

    float q[64], out[64];
#pragma unroll
    for (int p8 = 0; p8 < 8; ++p8) {
        uint4 w = *(const uint4*)&sQ[t*72 + p8*8];
        uint uu[4] = {w.x, w.y, w.z, w.w};
#pragma unroll
        for (int e = 0; e < 4; ++e) {
            q[p8*8 + e*2]     = b2f((ushort)(uu[e] & 0xffffu));
            q[p8*8 + e*2 + 1] = b2f((ushort)(uu[e] >> 16));
        }
    }
#pragma unroll
    for (int p = 0; p < 64; ++p) out[p] = 0.f;

    // out[p] = sum_a k[a] * q[(p - a) mod (8,8)]
#pragma unroll
    for (int a = 0; a < 64; ++a) {
        float kv = b2f(sK[t*72 + a]);
        const int a0 = a >> 3, a1 = a & 7;
#pragma unroll
        for (int p = 0; p < 64; ++p) {
            int qi = ((((p >> 3) - a0) & 7) << 3) | (((p & 7) - a1) & 7);
            out[p] += kv * q[qi];
        }
    }

    // LN2 over c: lanes (head*32 .. head*32+31) form contiguous 32-lane groups
    float scl = ln2_s[c], bia = ln2_b[c];
#pragma unroll
    for (int p = 0; p < 64; ++p) {
        float s1 = out[p], s2 = out[p]*out[p];
#pragma unroll
        for (int mask = 1; mask <= 16; mask <<= 1) {
            s1 += __shfl_xor(s1, mask, 64);
            s2 += __shfl_xor(s2, mask, 64);
        }
        float mu = s1 * 0.03125f;
        float var = s2 * 0.03125f - mu*mu;
        float inv = rsqrtf(var + 1e-6f);
        out[p] = (out[p] - mu) * inv * scl + bia;
    }

    __syncthreads();
    // stage V into sQ (Q fully consumed)
#pragma unroll
    for (int it = 0; it < 8; ++it) {
        int ci = it*256 + t;
        int cc = ci >> 6, p = ci & 63;
        uint4 wv = ((const uint4*)Vrow)[ci];
        uint uv[4] = {wv.x, wv.y, wv.z, wv.w};
#pragma unroll
        for (int e = 0; e < 4; ++e) {
            sQ[((2*e  )*32 + cc)*72 + p] = (ushort)(uv[e] & 0xffffu);
            sQ[((2*e+1)*32 + cc)*72 + p] = (ushort)(uv[e] >> 16);
        }
    }
    __syncthreads();

    // gate + pack: A2[m][p*256 + head*32 + c]
    ushort* A2row = A2 + (size_t)m * 16384;
#pragma unroll
    for (int p = 0; p < 64; ++p) {
        float vv = b2f(sQ[t*72 + p]);
        A2row[p*256 + t] = f2b(vv * out[p]);
    }
}

// ---------------------------------------------------------------------------
// d_out = x + bo[c*64 + (h&7)*8 + (w&7)]   (residual + output bias, pre-GEMM2)
// ---------------------------------------------------------------------------
__global__ __launch_bounds__(256) void init_out(
    const float* __restrict__ x, const float* __restrict__ bo,
    float* __restrict__ out) {
    int idx = blockIdx.x * 256 + threadIdx.x;
    int cc = idx & 31, w = (idx >> 5) & 255, h = (idx >> 13) & 255;
    out[idx] = x[idx] + bo[cc*64 + (h&7)*8 + (w&7)];
}

// ---------------------------------------------------------------------------
extern "C" void kernel_launch(void* const* d_in, const int* in_sizes, int n_in,
                              void* d_out, int out_size, void* d_ws, size_t ws_size,
                              hipStream_t stream) {
    (void)in_sizes; (void)n_in; (void)out_size; (void)ws_size;
    const float* x    = (const float*)d_in[0];
    const float* ln1s = (const float*)d_in[1];
    const float* ln1b = (const float*)d_in[2];
    const float* Wq   = (const float*)d_in[3];
    const float* bq   = (const float*)d_in[4];
    const float* Wk   = (const float*)d_in[5];
    const float* bk   = (const float*)d_in[6];
    const float* Wv   = (const float*)d_in[7];
    const float* bv   = (const float*)d_in[8];
    const float* ln2s = (const float*)d_in[9];
    const float* ln2b = (const float*)d_in[10];
    const float* Wo   = (const float*)d_in[11];
    const float* bo   = (const float*)d_in[12];
    float* out = (float*)d_out;

    char* ws = (char*)d_ws;
    ushort* A1 = (ushort*)(ws);                      //  8.0 MB  [2048,2048] bf16
    ushort* WT = (ushort*)(ws + 8388608);            // 64.0 MB  [N,K] bf16
    ushort* Qb = (ushort*)(ws + 75497472);           // 64.0 MB  [2048,16384] bf16
    ushort* Kb = (ushort*)(ws + 142606336);          // 64.0 MB
    ushort* Vb = (ushort*)(ws + 209715200);          // 64.0 MB  (end 276.8 MB)
    ushort* A2 = Qb;                                 // aliases Qb (safe: per-row)

    ln1_pack<<<512, 256, 0, stream>>>(x, ln1s, ln1b, A1);

    wcvt<<<dim3(256, 32), 256, 0, stream>>>(Wq, WT, 2048, 16384);
    gemm_bt<0><<<dim3(128, 16), 256, 0, stream>>>(A1, WT, bq, Qb, nullptr,
                                                  2048, 16384, 2048, 2048);
    wcvt<<<dim3(256, 32), 256, 0, stream>>>(Wk, WT, 2048, 16384);
    gemm_bt<0><<<dim3(128, 16), 256, 0, stream>>>(A1, WT, bk, Kb, nullptr,
                                                  2048, 16384, 2048, 2048);
    wcvt<<<dim3(256, 32), 256, 0, stream>>>(Wv, WT, 2048, 16384);
    gemm_bt<0><<<dim3(128, 16), 256, 0, stream>>>(A1, WT, bv, Vb, nullptr,
                                                  2048, 16384, 2048, 2048);

    conv_gate<<<2048, 256, 0, stream>>>(Qb, Kb, Vb, ln2s, ln2b, A2);

    wcvt<<<dim3(32, 256), 256, 0, stream>>>(Wo, WT, 16384, 2048);
    init_out<<<16384, 256, 0, stream>>>(x, bo, out);
    gemm_bt<1><<<dim3(16, 16, 4), 256, 0, stream>>>(A2, WT, nullptr, nullptr, out,
                                                    2048, 2048, 16384, 4096);
}

// Round 2
// 1814.125 us; speedup vs baseline: 1.4293x; 1.4293x over previous
//
#include <hip/hip_runtime.h>
#include <hip/hip_bf16.h>
#include <cstdint>

// ---------------------------------------------------------------------------
// Types / helpers
// ---------------------------------------------------------------------------
typedef __bf16 bf16_t;
typedef __attribute__((ext_vector_type(8))) __bf16 bf16x8;
typedef __attribute__((ext_vector_type(4))) float f32x4;

__device__ __forceinline__ float b2f(ushort u) {
    union { float f; uint32_t i; } x; x.i = ((uint32_t)u) << 16; return x.f;
}
__device__ __forceinline__ ushort f2b(float f) {
    uint32_t i = __builtin_bit_cast(uint32_t, f);
    uint32_t r = (i + 0x7FFFu + ((i >> 16) & 1u)) >> 16;   // RNE
    return (ushort)r;
}

// async global->LDS, 16 bytes per lane; lds ptr must be wave-uniform base
__device__ __forceinline__ void g2l16(const ushort* gp, ushort* lp) {
    __builtin_amdgcn_global_load_lds(
        (const __attribute__((address_space(1))) uint32_t*)gp,
        (__attribute__((address_space(3))) uint32_t*)lp, 16, 0, 0);
}

// ---------------------------------------------------------------------------
// LN1 + pack x into GEMM-A layout: A1[patch=(b*32+gh)*32+gw][(i*8+j)*32+c] bf16
// ---------------------------------------------------------------------------
__global__ __launch_bounds__(256) void ln1_pack(
    const float* __restrict__ x, const float* __restrict__ g,
    const float* __restrict__ b, ushort* __restrict__ A1) {
    int pix = blockIdx.x * 256 + threadIdx.x;      // 0..131071
    const float4* xp = (const float4*)(x + (size_t)pix * 32);
    float v[32]; float s = 0.f;
#pragma unroll
    for (int i = 0; i < 8; ++i) {
        float4 f = xp[i];
        v[i*4+0] = f.x; v[i*4+1] = f.y; v[i*4+2] = f.z; v[i*4+3] = f.w;
        s += f.x + f.y + f.z + f.w;
    }
    float mu = s * (1.f/32.f), s2 = 0.f;
#pragma unroll
    for (int i = 0; i < 32; ++i) { float d = v[i]-mu; s2 += d*d; }
    float inv = rsqrtf(s2 * (1.f/32.f) + 1e-6f);
    int w = pix & 255, h = (pix >> 8) & 255, bb = pix >> 16;
    size_t row = ((size_t)bb*32 + (h>>3))*32 + (w>>3);
    ushort* dst = A1 + row*2048 + (size_t)((h&7)*8 + (w&7))*32;
    ushort o[32];
#pragma unroll
    for (int i = 0; i < 32; ++i) o[i] = f2b((v[i]-mu)*inv*g[i] + b[i]);
    uint4* d4 = (uint4*)dst; const uint4* s4 = (const uint4*)o;
#pragma unroll
    for (int i = 0; i < 4; ++i) d4[i] = s4[i];
}

// ---------------------------------------------------------------------------
// Weight fp32 [K,N] (n-contig) -> bf16 [N,K] (k-contig) transpose+convert
// ---------------------------------------------------------------------------
__global__ __launch_bounds__(256) void wcvt(
    const float* __restrict__ W, ushort* __restrict__ WT, int K, int N) {
    __shared__ float tile[64][65];
    int n0 = blockIdx.x * 64, k0 = blockIdx.y * 64;
    int t = threadIdx.x;
    int col4 = (t & 15) * 4, krow = t >> 4;
#pragma unroll
    for (int it = 0; it < 4; ++it) {
        int kk = it*16 + krow;
        float4 f = *(const float4*)(W + (size_t)(k0+kk)*N + n0 + col4);
        tile[kk][col4+0] = f.x; tile[kk][col4+1] = f.y;
        tile[kk][col4+2] = f.z; tile[kk][col4+3] = f.w;
    }
    __syncthreads();
    int n = t >> 2, ch = t & 3;
    ushort o[16];
#pragma unroll
    for (int i = 0; i < 16; ++i) o[i] = f2b(tile[ch*16 + i][n]);
    uint4* dst = (uint4*)(WT + (size_t)(n0+n)*K + k0 + ch*16);
    dst[0] = ((const uint4*)o)[0];
    dst[1] = ((const uint4*)o)[1];
}

// ---------------------------------------------------------------------------
// bf16 MFMA GEMM: C[M,N] = A[M,K] * Bt[N,K]^T, 128x128 tile, BK=32
// Grid: blockIdx.x = m-tile (fastest -> co-resident blocks share the B-tile,
//       keeping WT L2/L3-hot), blockIdx.y = n-tile, blockIdx.z = K-split.
// EPI=0: C = acc + bias[n] -> bf16 Cb, via per-wave LDS transpose + uint4
// EPI=1: fp32 split-K partial tile -> Out + z*M*N, coalesced scalar f32
// ---------------------------------------------------------------------------
template <int EPI>
__global__ __launch_bounds__(256, 2) void gemm_bt(
    const ushort* __restrict__ A, const ushort* __restrict__ Bt,
    const float* __restrict__ bias, ushort* __restrict__ Cb,
    float* __restrict__ Out, int M, int N, int K, int KS) {
    __shared__ __align__(16) ushort sA[128*32];
    __shared__ __align__(16) ushort sB[128*32];
    const int tid = threadIdx.x;
    const int wave = tid >> 6, lane = tid & 63;
    const int lrow = lane & 15, lquad = lane >> 4;
    const int m0 = blockIdx.x * 128, n0 = blockIdx.y * 128;
    const int wm = (wave & 1) * 64, wn = (wave >> 1) * 64;

    // staging map: chunk ci -> LDS pos (r, q'); global kquad = q' ^ ((r>>1)&3)
    const int r0 = tid >> 2,        q0 = (tid & 3) ^ ((r0 >> 1) & 3);
    const int r1 = (256+tid) >> 2,  q1 = (tid & 3) ^ ((r1 >> 1) & 3);
    ushort* lA0 = sA + wave*512;          ushort* lA1 = sA + 2048 + wave*512;
    ushort* lB0 = sB + wave*512;          ushort* lB1 = sB + 2048 + wave*512;
    const size_t aRow0 = (size_t)(m0 + r0) * K, aRow1 = (size_t)(m0 + r1) * K;
    const size_t bRow0 = (size_t)(n0 + r0) * K, bRow1 = (size_t)(n0 + r1) * K;

    // fragment LDS addresses (constant per thread)
    const ushort* aAddr[4]; const ushort* bAddr[4];
#pragma unroll
    for (int i = 0; i < 4; ++i) {
        int r = wm + i*16 + lrow;
        aAddr[i] = sA + r*32 + ((lquad ^ ((r >> 1) & 3)) * 8);
        int nn = wn + i*16 + lrow;
        bAddr[i] = sB + nn*32 + ((lquad ^ ((nn >> 1) & 3)) * 8);
    }

    f32x4 acc[4][4];
#pragma unroll
    for (int i = 0; i < 4; ++i)
#pragma unroll
        for (int j = 0; j < 4; ++j) acc[i][j] = f32x4{0.f, 0.f, 0.f, 0.f};

    const int kbeg = (EPI == 1) ? blockIdx.z * KS : 0;
    const int kend = kbeg + KS;
    for (int kt = kbeg; kt < kend; kt += 32) {
        __syncthreads();
        g2l16(A  + aRow0 + kt + q0*8, lA0);
        g2l16(A  + aRow1 + kt + q1*8, lA1);
        g2l16(Bt + bRow0 + kt + q0*8, lB0);
        g2l16(Bt + bRow1 + kt + q1*8, lB1);
        __syncthreads();
        bf16x8 af[4], bg[4];
#pragma unroll
        for (int i = 0; i < 4; ++i) {
            af[i] = __builtin_bit_cast(bf16x8, *(const uint4*)aAddr[i]);
            bg[i] = __builtin_bit_cast(bf16x8, *(const uint4*)bAddr[i]);
        }
#pragma unroll
        for (int i = 0; i < 4; ++i)
#pragma unroll
            for (int j = 0; j < 4; ++j)
                acc[i][j] = __builtin_amdgcn_mfma_f32_16x16x32_bf16(
                    af[i], bg[j], acc[i][j], 0, 0, 0);
    }

    if constexpr (EPI == 0) {
        // bias per j-column
        float bvj[4];
#pragma unroll
        for (int j = 0; j < 4; ++j) bvj[j] = bias[n0 + wn + j*16 + lrow];
        __syncthreads();                    // all waves done reading sA/sB
        ushort* warena = sA + wave * 2048;  // 4 KB per wave: 32 rows x 64 cols
#pragma unroll
        for (int pass = 0; pass < 2; ++pass) {
#pragma unroll
            for (int ih = 0; ih < 2; ++ih) {
                const int i = pass*2 + ih;
#pragma unroll
                for (int j = 0; j < 4; ++j)
#pragma unroll
                    for (int re = 0; re < 4; ++re) {
                        int mrow = ih*16 + lquad*4 + re;     // 0..31
                        int col  = j*16 + lrow;              // 0..63
                        warena[mrow*64 + col] = f2b(acc[i][j][re] + bvj[j]);
                    }
            }
            // intra-wave only (lockstep) -> no barrier needed
#pragma unroll
            for (int t2 = 0; t2 < 4; ++t2) {
                int chunk = t2*64 + lane;          // 0..255
                int row = chunk >> 3, seg = chunk & 7;
                uint4 v = *(const uint4*)&warena[row*64 + seg*8];
                *(uint4*)&Cb[(size_t)(m0 + wm + pass*32 + row)*N
                             + n0 + wn + seg*8] = v;
            }
        }
    } else {
        float* P = Out + (size_t)blockIdx.z * M * N;
#pragma unroll
        for (int j = 0; j < 4; ++j) {
            int n = n0 + wn + j*16 + lrow;
#pragma unroll
            for (int i = 0; i < 4; ++i) {
                int mbase = m0 + wm + i*16 + lquad*4;
#pragma unroll
                for (int re = 0; re < 4; ++re)
                    P[(size_t)(mbase + re)*N + n] = acc[i][j][re];
            }
        }
    }
}

// ---------------------------------------------------------------------------
// Per-patch: 8x8 circular conv (q ⊛ k), LN2 over c, gate by v, pack A2 rows.
// One block per patch; thread t -> (head = t>>5, c = t&31). A2 may alias Qb.
// ---------------------------------------------------------------------------
__global__ __launch_bounds__(256, 2) void conv_gate(
    const ushort* __restrict__ Qb, const ushort* __restrict__ Kb,
    const ushort* __restrict__ Vb, const float* __restrict__ ln2_s,
    const float* __restrict__ ln2_b, ushort* __restrict__ A2) {
    __shared__ __align__(16) ushort sQ[256*72];    // [head*32+c][p], pad 72
    __shared__ __align__(16) ushort sK[256*72];
    const int t = threadIdx.x;
    const int m = blockIdx.x;
    const int c = t & 31;
    const ushort* Qrow = Qb + (size_t)m * 16384;
    const ushort* Krow = Kb + (size_t)m * 16384;
    const ushort* Vrow = Vb + (size_t)m * 16384;

    // stage Q,K: global element (c*512 + p*8 + head) -> sQ[(head*32+c)*72 + p]
#pragma unroll
    for (int it = 0; it < 8; ++it) {
        int ci = it*256 + t;
        int cc = ci >> 6, p = ci & 63;
        uint4 wq = ((const uint4*)Qrow)[ci];
        uint4 wk = ((const uint4*)Krow)[ci];
        uint uq[4] = {wq.x, wq.y, wq.z, wq.w};
        uint uk[4] = {wk.x, wk.y, wk.z, wk.w};
#pragma unroll
        for (int e = 0; e < 4; ++e) {
            sQ[((2*e  )*32 + cc)*72 + p] = (ushort)(uq[e] & 0xffffu);
            sQ[((2*e+1)*32 + cc)*72 + p] = (ushort)(uq[e] >> 16);
            sK[((2*e  )*32 + cc)*72 + p] = (ushort)(uk[e] & 0xffffu);
            sK[((2*e+1)*32 + cc)*72 + p] = (ushort)(uk[e] >> 16);
        }
    }
    __syncthreads();

    float q[64], out[64];
#pragma unroll
    for (int p8 = 0; p8 < 8; ++p8) {
        uint4 w = *(const uint4*)&sQ[t*72 + p8*8];
        uint uu[4] = {w.x, w.y, w.z, w.w};
#pragma unroll
        for (int e = 0; e < 4; ++e) {
            q[p8*8 + e*2]     = b2f((ushort)(uu[e] & 0xffffu));
            q[p8*8 + e*2 + 1] = b2f((ushort)(uu[e] >> 16));
        }
    }
#pragma unroll
    for (int p = 0; p < 64; ++p) out[p] = 0.f;

    // out[p] = sum_a k[a] * q[(p - a) mod (8,8)]
#pragma unroll
    for (int a = 0; a < 64; ++a) {
        float kv = b2f(sK[t*72 + a]);
        const int a0 = a >> 3, a1 = a & 7;
#pragma unroll
        for (int p = 0; p < 64; ++p) {
            int qi = ((((p >> 3) - a0) & 7) << 3) | (((p & 7) - a1) & 7);
            out[p] += kv * q[qi];
        }
    }

    // LN2 over c: lanes (head*32 .. head*32+31) form contiguous 32-lane groups
    float scl = ln2_s[c], bia = ln2_b[c];
#pragma unroll
    for (int p = 0; p < 64; ++p) {
        float s1 = out[p], s2 = out[p]*out[p];
#pragma unroll
        for (int mask = 1; mask <= 16; mask <<= 1) {
            s1 += __shfl_xor(s1, mask, 64);
            s2 += __shfl_xor(s2, mask, 64);
        }
        float mu = s1 * 0.03125f;
        float var = s2 * 0.03125f - mu*mu;
        float inv = rsqrtf(var + 1e-6f);
        out[p] = (out[p] - mu) * inv * scl + bia;
    }

    __syncthreads();
    // stage V into sQ (Q fully consumed)
#pragma unroll
    for (int it = 0; it < 8; ++it) {
        int ci = it*256 + t;
        int cc = ci >> 6, p = ci & 63;
        uint4 wv = ((const uint4*)Vrow)[ci];
        uint uv[4] = {wv.x, wv.y, wv.z, wv.w};
#pragma unroll
        for (int e = 0; e < 4; ++e) {
            sQ[((2*e  )*32 + cc)*72 + p] = (ushort)(uv[e] & 0xffffu);
            sQ[((2*e+1)*32 + cc)*72 + p] = (ushort)(uv[e] >> 16);
        }
    }
    __syncthreads();

    // gate + pack: A2[m][p*256 + head*32 + c]
    ushort* A2row = A2 + (size_t)m * 16384;
#pragma unroll
    for (int p = 0; p < 64; ++p) {
        float vv = b2f(sQ[t*72 + p]);
        A2row[p*256 + t] = f2b(vv * out[p]);
    }
}

// ---------------------------------------------------------------------------
// reduce_out: out[pix] = x[pix] + bo[n] + sum_z P[z][m][n], patch->pixel remap
// One block per patch m. P rows read coalesced; out written coalesced.
// ---------------------------------------------------------------------------
__global__ __launch_bounds__(256) void reduce_out(
    const float* __restrict__ Pp, const float* __restrict__ x,
    const float* __restrict__ bo, float* __restrict__ out) {
    __shared__ float sn[32*65];                    // padded [c][64]
    const int t = threadIdx.x, m = blockIdx.x;
    float4 s0 = {0.f,0.f,0.f,0.f}, s1 = {0.f,0.f,0.f,0.f};
#pragma unroll
    for (int z = 0; z < 4; ++z) {
        const float4* base =
            (const float4*)(Pp + ((size_t)z*2048 + m) * 2048);
        float4 u = base[t], v = base[256 + t];
        s0.x += u.x; s0.y += u.y; s0.z += u.z; s0.w += u.w;
        s1.x += v.x; s1.y += v.y; s1.z += v.z; s1.w += v.w;
    }
    {
        int na = t*4;                              // chunk t   -> n = 4t
        int nb = (256 + t)*4;                      // chunk 256+t
        float va[4] = {s0.x, s0.y, s0.z, s0.w};
        float vb[4] = {s1.x, s1.y, s1.z, s1.w};
#pragma unroll
        for (int e = 0; e < 4; ++e) {
            int n1 = na + e, n2 = nb + e;
            sn[(n1 >> 6)*65 + (n1 & 63)] = va[e];
            sn[(n2 >> 6)*65 + (n2 & 63)] = vb[e];
        }
    }
    __syncthreads();
    const int c = t & 31, pi = t >> 5;
    const int bb = m >> 10, gh = (m >> 5) & 31, gw = m & 31;
#pragma unroll
    for (int it = 0; it < 8; ++it) {
        int p = it*8 + pi;                         // 0..63
        int p0 = p >> 3, p1 = p & 7;
        int n = c*64 + p;
        size_t oi = ((size_t)((bb*256 + gh*8 + p0)*256 + gw*8 + p1))*32 + c;
        out[oi] = x[oi] + bo[n] + sn[c*65 + p];
    }
}

// ---------------------------------------------------------------------------
extern "C" void kernel_launch(void* const* d_in, const int* in_sizes, int n_in,
                              void* d_out, int out_size, void* d_ws, size_t ws_size,
                              hipStream_t stream) {
    (void)in_sizes; (void)n_in; (void)out_size; (void)ws_size;
    const float* x    = (const float*)d_in[0];
    const float* ln1s = (const float*)d_in[1];
    const float* ln1b = (const float*)d_in[2];
    const float* Wq   = (const float*)d_in[3];
    const float* bq   = (const float*)d_in[4];
    const float* Wk   = (const float*)d_in[5];
    const float* bk   = (const float*)d_in[6];
    const float* Wv   = (const float*)d_in[7];
    const float* bv   = (const float*)d_in[8];
    const float* ln2s = (const float*)d_in[9];
    const float* ln2b = (const float*)d_in[10];
    const float* Wo   = (const float*)d_in[11];
    const float* bo   = (const float*)d_in[12];
    float* out = (float*)d_out;

    char* ws = (char*)d_ws;
    ushort* A1 = (ushort*)(ws);                      //  8.0 MB  [2048,2048] bf16
    ushort* WT = (ushort*)(ws + 8388608);            // 64.0 MB  [N,K] bf16
    ushort* Qb = (ushort*)(ws + 75497472);           // 64.0 MB  [2048,16384] bf16
    ushort* Kb = (ushort*)(ws + 142606336);          // 64.0 MB
    ushort* Vb = (ushort*)(ws + 209715200);          // 64.0 MB  (end 276.8 MB)
    ushort* A2 = Qb;                                 // aliases Qb (safe: per-row)
    float*  Pp = (float*)Kb;                         // 64.0 MB split-K partials
                                                     // (Kb dead after conv_gate)

    ln1_pack<<<512, 256, 0, stream>>>(x, ln1s, ln1b, A1);

    wcvt<<<dim3(256, 32), 256, 0, stream>>>(Wq, WT, 2048, 16384);
    gemm_bt<0><<<dim3(16, 128), 256, 0, stream>>>(A1, WT, bq, Qb, nullptr,
                                                  2048, 16384, 2048, 2048);
    wcvt<<<dim3(256, 32), 256, 0, stream>>>(Wk, WT, 2048, 16384);
    gemm_bt<0><<<dim3(16, 128), 256, 0, stream>>>(A1, WT, bk, Kb, nullptr,
                                                  2048, 16384, 2048, 2048);
    wcvt<<<dim3(256, 32), 256, 0, stream>>>(Wv, WT, 2048, 16384);
    gemm_bt<0><<<dim3(16, 128), 256, 0, stream>>>(A1, WT, bv, Vb, nullptr,
                                                  2048, 16384, 2048, 2048);

    conv_gate<<<2048, 256, 0, stream>>>(Qb, Kb, Vb, ln2s, ln2b, A2);

    wcvt<<<dim3(32, 256), 256, 0, stream>>>(Wo, WT, 16384, 2048);
    gemm_bt<1><<<dim3(16, 16, 4), 256, 0, stream>>>(A2, WT, nullptr, nullptr, Pp,
                                                    2048, 2048, 16384, 4096);
    reduce_out<<<2048, 256, 0, stream>>>(Pp, x, bo, out);
}

// Round 3
// 1400.502 us; speedup vs baseline: 1.8514x; 1.2953x over previous
//
#include <hip/hip_runtime.h>
#include <hip/hip_bf16.h>
#include <cstdint>

// ---------------------------------------------------------------------------
// Types / helpers
// ---------------------------------------------------------------------------
typedef __bf16 bf16_t;
typedef __attribute__((ext_vector_type(8))) __bf16 bf16x8;
typedef __attribute__((ext_vector_type(4))) float f32x4;

__device__ __forceinline__ float b2f(ushort u) {
    union { float f; uint32_t i; } x; x.i = ((uint32_t)u) << 16; return x.f;
}
__device__ __forceinline__ ushort f2b(float f) {
    uint32_t i = __builtin_bit_cast(uint32_t, f);
    uint32_t r = (i + 0x7FFFu + ((i >> 16) & 1u)) >> 16;   // RNE
    return (ushort)r;
}

// async global->LDS, 16 bytes per lane; lds ptr must be wave-uniform base
__device__ __forceinline__ void g2l16(const ushort* gp, ushort* lp) {
    __builtin_amdgcn_global_load_lds(
        (const __attribute__((address_space(1))) uint32_t*)gp,
        (__attribute__((address_space(3))) uint32_t*)lp, 16, 0, 0);
}

// ---------------------------------------------------------------------------
// LN1 + pack x into GEMM-A layout: A1[patch=(b*32+gh)*32+gw][(i*8+j)*32+c] bf16
// ---------------------------------------------------------------------------
__global__ __launch_bounds__(256) void ln1_pack(
    const float* __restrict__ x, const float* __restrict__ g,
    const float* __restrict__ b, ushort* __restrict__ A1) {
    int pix = blockIdx.x * 256 + threadIdx.x;      // 0..131071
    const float4* xp = (const float4*)(x + (size_t)pix * 32);
    float v[32]; float s = 0.f;
#pragma unroll
    for (int i = 0; i < 8; ++i) {
        float4 f = xp[i];
        v[i*4+0] = f.x; v[i*4+1] = f.y; v[i*4+2] = f.z; v[i*4+3] = f.w;
        s += f.x + f.y + f.z + f.w;
    }
    float mu = s * (1.f/32.f), s2 = 0.f;
#pragma unroll
    for (int i = 0; i < 32; ++i) { float d = v[i]-mu; s2 += d*d; }
    float inv = rsqrtf(s2 * (1.f/32.f) + 1e-6f);
    int w = pix & 255, h = (pix >> 8) & 255, bb = pix >> 16;
    size_t row = ((size_t)bb*32 + (h>>3))*32 + (w>>3);
    ushort* dst = A1 + row*2048 + (size_t)((h&7)*8 + (w&7))*32;
    ushort o[32];
#pragma unroll
    for (int i = 0; i < 32; ++i) o[i] = f2b((v[i]-mu)*inv*g[i] + b[i]);
    uint4* d4 = (uint4*)dst; const uint4* s4 = (const uint4*)o;
#pragma unroll
    for (int i = 0; i < 4; ++i) d4[i] = s4[i];
}

// ---------------------------------------------------------------------------
// Weight fp32 [K,N] (n-contig) -> bf16 [N,K] (k-contig) transpose+convert
// ---------------------------------------------------------------------------
__global__ __launch_bounds__(256) void wcvt(
    const float* __restrict__ W, ushort* __restrict__ WT, int K, int N) {
    __shared__ float tile[64][65];
    int n0 = blockIdx.x * 64, k0 = blockIdx.y * 64;
    int t = threadIdx.x;
    int col4 = (t & 15) * 4, krow = t >> 4;
#pragma unroll
    for (int it = 0; it < 4; ++it) {
        int kk = it*16 + krow;
        float4 f = *(const float4*)(W + (size_t)(k0+kk)*N + n0 + col4);
        tile[kk][col4+0] = f.x; tile[kk][col4+1] = f.y;
        tile[kk][col4+2] = f.z; tile[kk][col4+3] = f.w;
    }
    __syncthreads();
    int n = t >> 2, ch = t & 3;
    ushort o[16];
#pragma unroll
    for (int i = 0; i < 16; ++i) o[i] = f2b(tile[ch*16 + i][n]);
    uint4* dst = (uint4*)(WT + (size_t)(n0+n)*K + k0 + ch*16);
    dst[0] = ((const uint4*)o)[0];
    dst[1] = ((const uint4*)o)[1];
}

// ---------------------------------------------------------------------------
// bf16 MFMA GEMM: C[M,N] = A[M,K] * Bt[N,K]^T, 128x128 tile, BK=32
// Grid: blockIdx.x = m-tile (fastest -> co-resident blocks share the B-tile,
//       keeping WT L2/L3-hot), blockIdx.y = n-tile, blockIdx.z = K-split.
// EPI=0: C = acc + bias[n] -> bf16 Cb, via per-wave LDS transpose + uint4
// EPI=1: fp32 split-K partial tile -> Out + z*M*N, coalesced scalar f32
// ---------------------------------------------------------------------------
template <int EPI>
__global__ __launch_bounds__(256, 2) void gemm_bt(
    const ushort* __restrict__ A, const ushort* __restrict__ Bt,
    const float* __restrict__ bias, ushort* __restrict__ Cb,
    float* __restrict__ Out, int M, int N, int K, int KS) {
    __shared__ __align__(16) ushort sA[128*32];
    __shared__ __align__(16) ushort sB[128*32];
    const int tid = threadIdx.x;
    const int wave = tid >> 6, lane = tid & 63;
    const int lrow = lane & 15, lquad = lane >> 4;
    const int m0 = blockIdx.x * 128, n0 = blockIdx.y * 128;
    const int wm = (wave & 1) * 64, wn = (wave >> 1) * 64;

    // staging map: chunk ci -> LDS pos (r, q'); global kquad = q' ^ ((r>>1)&3)
    const int r0 = tid >> 2,        q0 = (tid & 3) ^ ((r0 >> 1) & 3);
    const int r1 = (256+tid) >> 2,  q1 = (tid & 3) ^ ((r1 >> 1) & 3);
    ushort* lA0 = sA + wave*512;          ushort* lA1 = sA + 2048 + wave*512;
    ushort* lB0 = sB + wave*512;          ushort* lB1 = sB + 2048 + wave*512;
    const size_t aRow0 = (size_t)(m0 + r0) * K, aRow1 = (size_t)(m0 + r1) * K;
    const size_t bRow0 = (size_t)(n0 + r0) * K, bRow1 = (size_t)(n0 + r1) * K;

    // fragment LDS addresses (constant per thread)
    const ushort* aAddr[4]; const ushort* bAddr[4];
#pragma unroll
    for (int i = 0; i < 4; ++i) {
        int r = wm + i*16 + lrow;
        aAddr[i] = sA + r*32 + ((lquad ^ ((r >> 1) & 3)) * 8);
        int nn = wn + i*16 + lrow;
        bAddr[i] = sB + nn*32 + ((lquad ^ ((nn >> 1) & 3)) * 8);
    }

    f32x4 acc[4][4];
#pragma unroll
    for (int i = 0; i < 4; ++i)
#pragma unroll
        for (int j = 0; j < 4; ++j) acc[i][j] = f32x4{0.f, 0.f, 0.f, 0.f};

    const int kbeg = (EPI == 1) ? blockIdx.z * KS : 0;
    const int kend = kbeg + KS;
    for (int kt = kbeg; kt < kend; kt += 32) {
        __syncthreads();
        g2l16(A  + aRow0 + kt + q0*8, lA0);
        g2l16(A  + aRow1 + kt + q1*8, lA1);
        g2l16(Bt + bRow0 + kt + q0*8, lB0);
        g2l16(Bt + bRow1 + kt + q1*8, lB1);
        __syncthreads();
        bf16x8 af[4], bg[4];
#pragma unroll
        for (int i = 0; i < 4; ++i) {
            af[i] = __builtin_bit_cast(bf16x8, *(const uint4*)aAddr[i]);
            bg[i] = __builtin_bit_cast(bf16x8, *(const uint4*)bAddr[i]);
        }
#pragma unroll
        for (int i = 0; i < 4; ++i)
#pragma unroll
            for (int j = 0; j < 4; ++j)
                acc[i][j] = __builtin_amdgcn_mfma_f32_16x16x32_bf16(
                    af[i], bg[j], acc[i][j], 0, 0, 0);
    }

    if constexpr (EPI == 0) {
        // bias per j-column
        float bvj[4];
#pragma unroll
        for (int j = 0; j < 4; ++j) bvj[j] = bias[n0 + wn + j*16 + lrow];
        __syncthreads();                    // all waves done reading sA/sB
        ushort* warena = sA + wave * 2048;  // 4 KB per wave: 32 rows x 64 cols
#pragma unroll
        for (int pass = 0; pass < 2; ++pass) {
#pragma unroll
            for (int ih = 0; ih < 2; ++ih) {
                const int i = pass*2 + ih;
#pragma unroll
                for (int j = 0; j < 4; ++j)
#pragma unroll
                    for (int re = 0; re < 4; ++re) {
                        int mrow = ih*16 + lquad*4 + re;     // 0..31
                        int col  = j*16 + lrow;              // 0..63
                        warena[mrow*64 + col] = f2b(acc[i][j][re] + bvj[j]);
                    }
            }
            // intra-wave only (lockstep) -> no barrier needed
#pragma unroll
            for (int t2 = 0; t2 < 4; ++t2) {
                int chunk = t2*64 + lane;          // 0..255
                int row = chunk >> 3, seg = chunk & 7;
                uint4 v = *(const uint4*)&warena[row*64 + seg*8];
                *(uint4*)&Cb[(size_t)(m0 + wm + pass*32 + row)*N
                             + n0 + wn + seg*8] = v;
            }
        }
    } else {
        float* P = Out + (size_t)blockIdx.z * M * N;
#pragma unroll
        for (int j = 0; j < 4; ++j) {
            int n = n0 + wn + j*16 + lrow;
#pragma unroll
            for (int i = 0; i < 4; ++i) {
                int mbase = m0 + wm + i*16 + lquad*4;
#pragma unroll
                for (int re = 0; re < 4; ++re)
                    P[(size_t)(mbase + re)*N + n] = acc[i][j][re];
            }
        }
    }
}

// ---------------------------------------------------------------------------
// Per-patch: 8x8 circular conv (q ⊛ k), LN2 over c, gate by v, pack A2 rows.
// One block per patch; thread t -> (head = t>>5, c = t&31). A2 may alias Qb.
// q[64], k[64] live in registers (compile-time indexed); per-p scalar acc ->
// immediate LN2 + gate + store. No out[64] array -> no spill (round-2 fix:
// symmetric ~1 GB FETCH/WRITE excess was scratch round-trip).
// ---------------------------------------------------------------------------
__global__ __launch_bounds__(256) void conv_gate(
    const ushort* __restrict__ Qb, const ushort* __restrict__ Kb,
    const ushort* __restrict__ Vb, const float* __restrict__ ln2_s,
    const float* __restrict__ ln2_b, ushort* __restrict__ A2) {
    __shared__ __align__(16) ushort sS[256*72];    // 36 KB: [head*32+c][p]
    const int t = threadIdx.x;
    const int m = blockIdx.x;
    const int c = t & 31;
    const ushort* Qrow = Qb + (size_t)m * 16384;
    const ushort* Krow = Kb + (size_t)m * 16384;
    const ushort* Vrow = Vb + (size_t)m * 16384;

    // ---- stage Q -> LDS (coalesced global, per-lane LDS scatter) ----------
    // uint4 index ci: element e2 of it -> head=e2, c=ci>>6, p=ci&63
#define STAGE(SRC)                                                         \
    {                                                                      \
        _Pragma("unroll")                                                  \
        for (int it = 0; it < 8; ++it) {                                   \
            int ci = it*256 + t;                                           \
            int cc = ci >> 6, p = ci & 63;                                 \
            uint4 w = ((const uint4*)(SRC))[ci];                           \
            uint uu[4] = {w.x, w.y, w.z, w.w};                             \
            _Pragma("unroll")                                              \
            for (int e = 0; e < 4; ++e) {                                  \
                sS[((2*e  )*32 + cc)*72 + p] = (ushort)(uu[e] & 0xffffu);  \
                sS[((2*e+1)*32 + cc)*72 + p] = (ushort)(uu[e] >> 16);      \
            }                                                              \
        }                                                                  \
    }

    float q[64], k[64];

    STAGE(Qrow);
    __syncthreads();
#pragma unroll
    for (int e = 0; e < 8; ++e) {
        uint4 w = *(const uint4*)&sS[t*72 + e*8];
        uint uu[4] = {w.x, w.y, w.z, w.w};
#pragma unroll
        for (int z = 0; z < 4; ++z) {
            q[e*8 + z*2]     = b2f((ushort)(uu[z] & 0xffffu));
            q[e*8 + z*2 + 1] = b2f((ushort)(uu[z] >> 16));
        }
    }
    __syncthreads();
    STAGE(Krow);
    __syncthreads();
#pragma unroll
    for (int e = 0; e < 8; ++e) {
        uint4 w = *(const uint4*)&sS[t*72 + e*8];
        uint uu[4] = {w.x, w.y, w.z, w.w};
#pragma unroll
        for (int z = 0; z < 4; ++z) {
            k[e*8 + z*2]     = b2f((ushort)(uu[z] & 0xffffu));
            k[e*8 + z*2 + 1] = b2f((ushort)(uu[z] >> 16));
        }
    }
    __syncthreads();
    STAGE(Vrow);     // V stays in LDS for the gating pass
    __syncthreads();
#undef STAGE

    const float scl = ln2_s[c], bia = ln2_b[c];
    ushort* A2row = A2 + (size_t)m * 16384;

#pragma unroll
    for (int p0 = 0; p0 < 8; ++p0) {
        // v octet for p = p0*8 .. p0*8+7
        float vv[8];
        {
            uint4 w = *(const uint4*)&sS[t*72 + p0*8];
            uint uu[4] = {w.x, w.y, w.z, w.w};
#pragma unroll
            for (int z = 0; z < 4; ++z) {
                vv[z*2]   = b2f((ushort)(uu[z] & 0xffffu));
                vv[z*2+1] = b2f((ushort)(uu[z] >> 16));
            }
        }
#pragma unroll
        for (int p1 = 0; p1 < 8; ++p1) {
            float a0v = 0.f, a1v = 0.f, a2v = 0.f, a3v = 0.f;
#pragma unroll
            for (int b0 = 0; b0 < 8; ++b0) {
                const int qr = ((p0 - b0) & 7) * 8;
#pragma unroll
                for (int b1 = 0; b1 < 8; ++b1) {
                    float prod = k[b0*8 + b1] * q[qr + ((p1 - b1) & 7)];
                    if ((b0 & 3) == 0) a0v += prod;
                    else if ((b0 & 3) == 1) a1v += prod;
                    else if ((b0 & 3) == 2) a2v += prod;
                    else a3v += prod;
                }
            }
            float o = (a0v + a1v) + (a2v + a3v);
            // LN2 over the 32 channels of this head (lanes grouped by 32)
            float s1 = o, s2 = o * o;
#pragma unroll
            for (int mask = 1; mask <= 16; mask <<= 1) {
                s1 += __shfl_xor(s1, mask, 64);
                s2 += __shfl_xor(s2, mask, 64);
            }
            float mu = s1 * 0.03125f;
            float var = s2 * 0.03125f - mu * mu;
            float inv = rsqrtf(var + 1e-6f);
            float on = (o - mu) * inv * scl + bia;
            A2row[(p0*8 + p1)*256 + t] = f2b(vv[p1] * on);
        }
    }
}

// ---------------------------------------------------------------------------
// reduce_out: out[pix] = x[pix] + bo[n] + sum_z P[z][m][n], patch->pixel remap
// One block per patch m. P rows read coalesced; out written coalesced.
// ---------------------------------------------------------------------------
__global__ __launch_bounds__(256) void reduce_out(
    const float* __restrict__ Pp, const float* __restrict__ x,
    const float* __restrict__ bo, float* __restrict__ out) {
    __shared__ float sn[32*65];                    // padded [c][64]
    const int t = threadIdx.x, m = blockIdx.x;
    float4 s0 = {0.f,0.f,0.f,0.f}, s1 = {0.f,0.f,0.f,0.f};
#pragma unroll
    for (int z = 0; z < 4; ++z) {
        const float4* base =
            (const float4*)(Pp + ((size_t)z*2048 + m) * 2048);
        float4 u = base[t], v = base[256 + t];
        s0.x += u.x; s0.y += u.y; s0.z += u.z; s0.w += u.w;
        s1.x += v.x; s1.y += v.y; s1.z += v.z; s1.w += v.w;
    }
    {
        int na = t*4;                              // chunk t   -> n = 4t
        int nb = (256 + t)*4;                      // chunk 256+t
        float va[4] = {s0.x, s0.y, s0.z, s0.w};
        float vb[4] = {s1.x, s1.y, s1.z, s1.w};
#pragma unroll
        for (int e = 0; e < 4; ++e) {
            int n1 = na + e, n2 = nb + e;
            sn[(n1 >> 6)*65 + (n1 & 63)] = va[e];
            sn[(n2 >> 6)*65 + (n2 & 63)] = vb[e];
        }
    }
    __syncthreads();
    const int c = t & 31, pi = t >> 5;
    const int bb = m >> 10, gh = (m >> 5) & 31, gw = m & 31;
#pragma unroll
    for (int it = 0; it < 8; ++it) {
        int p = it*8 + pi;                         // 0..63
        int p0 = p >> 3, p1 = p & 7;
        int n = c*64 + p;
        size_t oi = ((size_t)((bb*256 + gh*8 + p0)*256 + gw*8 + p1))*32 + c;
        out[oi] = x[oi] + bo[n] + sn[c*65 + p];
    }
}

// ---------------------------------------------------------------------------
extern "C" void kernel_launch(void* const* d_in, const int* in_sizes, int n_in,
                              void* d_out, int out_size, void* d_ws, size_t ws_size,
                              hipStream_t stream) {
    (void)in_sizes; (void)n_in; (void)out_size; (void)ws_size;
    const float* x    = (const float*)d_in[0];
    const float* ln1s = (const float*)d_in[1];
    const float* ln1b = (const float*)d_in[2];
    const float* Wq   = (const float*)d_in[3];
    const float* bq   = (const float*)d_in[4];
    const float* Wk   = (const float*)d_in[5];
    const float* bk   = (const float*)d_in[6];
    const float* Wv   = (const float*)d_in[7];
    const float* bv   = (const float*)d_in[8];
    const float* ln2s = (const float*)d_in[9];
    const float* ln2b = (const float*)d_in[10];
    const float* Wo   = (const float*)d_in[11];
    const float* bo   = (const float*)d_in[12];
    float* out = (float*)d_out;

    char* ws = (char*)d_ws;
    ushort* A1 = (ushort*)(ws);                      //  8.0 MB  [2048,2048] bf16
    ushort* WT = (ushort*)(ws + 8388608);            // 64.0 MB  [N,K] bf16
    ushort* Qb = (ushort*)(ws + 75497472);           // 64.0 MB  [2048,16384] bf16
    ushort* Kb = (ushort*)(ws + 142606336);          // 64.0 MB
    ushort* Vb = (ushort*)(ws + 209715200);          // 64.0 MB  (end 276.8 MB)
    ushort* A2 = Qb;                                 // aliases Qb (safe: per-row)
    float*  Pp = (float*)Kb;                         // 64.0 MB split-K partials
                                                     // (Kb dead after conv_gate)

    ln1_pack<<<512, 256, 0, stream>>>(x, ln1s, ln1b, A1);

    wcvt<<<dim3(256, 32), 256, 0, stream>>>(Wq, WT, 2048, 16384);
    gemm_bt<0><<<dim3(16, 128), 256, 0, stream>>>(A1, WT, bq, Qb, nullptr,
                                                  2048, 16384, 2048, 2048);
    wcvt<<<dim3(256, 32), 256, 0, stream>>>(Wk, WT, 2048, 16384);
    gemm_bt<0><<<dim3(16, 128), 256, 0, stream>>>(A1, WT, bk, Kb, nullptr,
                                                  2048, 16384, 2048, 2048);
    wcvt<<<dim3(256, 32), 256, 0, stream>>>(Wv, WT, 2048, 16384);
    gemm_bt<0><<<dim3(16, 128), 256, 0, stream>>>(A1, WT, bv, Vb, nullptr,
                                                  2048, 16384, 2048, 2048);

    conv_gate<<<2048, 256, 0, stream>>>(Qb, Kb, Vb, ln2s, ln2b, A2);

    wcvt<<<dim3(32, 256), 256, 0, stream>>>(Wo, WT, 16384, 2048);
    gemm_bt<1><<<dim3(16, 16, 4), 256, 0, stream>>>(A2, WT, nullptr, nullptr, Pp,
                                                    2048, 2048, 16384, 4096);
    reduce_out<<<2048, 256, 0, stream>>>(Pp, x, bo, out);
}

// Round 4
// 1375.219 us; speedup vs baseline: 1.8855x; 1.0184x over previous
//
#include <hip/hip_runtime.h>
#include <hip/hip_bf16.h>
#include <cstdint>

// ---------------------------------------------------------------------------
// Types / helpers
// ---------------------------------------------------------------------------
typedef __bf16 bf16_t;
typedef __attribute__((ext_vector_type(8))) __bf16 bf16x8;
typedef __attribute__((ext_vector_type(4))) float f32x4;

__device__ __forceinline__ float b2f(ushort u) {
    union { float f; uint32_t i; } x; x.i = ((uint32_t)u) << 16; return x.f;
}
__device__ __forceinline__ ushort f2b(float f) {
    uint32_t i = __builtin_bit_cast(uint32_t, f);
    uint32_t r = (i + 0x7FFFu + ((i >> 16) & 1u)) >> 16;   // RNE
    return (ushort)r;
}

// async global->LDS, 16 bytes per lane; lds ptr must be wave-uniform base
__device__ __forceinline__ void g2l16(const ushort* gp, ushort* lp) {
    __builtin_amdgcn_global_load_lds(
        (const __attribute__((address_space(1))) uint32_t*)gp,
        (__attribute__((address_space(3))) uint32_t*)lp, 16, 0, 0);
}

// ---------------------------------------------------------------------------
// LN1 + pack x into GEMM-A layout: A1[patch=(b*32+gh)*32+gw][(i*8+j)*32+c] bf16
// ---------------------------------------------------------------------------
__global__ __launch_bounds__(256) void ln1_pack(
    const float* __restrict__ x, const float* __restrict__ g,
    const float* __restrict__ b, ushort* __restrict__ A1) {
    int pix = blockIdx.x * 256 + threadIdx.x;      // 0..131071
    const float4* xp = (const float4*)(x + (size_t)pix * 32);
    float v[32]; float s = 0.f;
#pragma unroll
    for (int i = 0; i < 8; ++i) {
        float4 f = xp[i];
        v[i*4+0] = f.x; v[i*4+1] = f.y; v[i*4+2] = f.z; v[i*4+3] = f.w;
        s += f.x + f.y + f.z + f.w;
    }
    float mu = s * (1.f/32.f), s2 = 0.f;
#pragma unroll
    for (int i = 0; i < 32; ++i) { float d = v[i]-mu; s2 += d*d; }
    float inv = rsqrtf(s2 * (1.f/32.f) + 1e-6f);
    int w = pix & 255, h = (pix >> 8) & 255, bb = pix >> 16;
    size_t row = ((size_t)bb*32 + (h>>3))*32 + (w>>3);
    ushort* dst = A1 + row*2048 + (size_t)((h&7)*8 + (w&7))*32;
    ushort o[32];
#pragma unroll
    for (int i = 0; i < 32; ++i) o[i] = f2b((v[i]-mu)*inv*g[i] + b[i]);
    uint4* d4 = (uint4*)dst; const uint4* s4 = (const uint4*)o;
#pragma unroll
    for (int i = 0; i < 4; ++i) d4[i] = s4[i];
}

// ---------------------------------------------------------------------------
// Weight fp32 [K,N] (n-contig) -> bf16 [N,K] (k-contig) transpose+convert
// ---------------------------------------------------------------------------
__global__ __launch_bounds__(256) void wcvt(
    const float* __restrict__ W, ushort* __restrict__ WT, int K, int N) {
    __shared__ float tile[64][65];
    int n0 = blockIdx.x * 64, k0 = blockIdx.y * 64;
    int t = threadIdx.x;
    int col4 = (t & 15) * 4, krow = t >> 4;
#pragma unroll
    for (int it = 0; it < 4; ++it) {
        int kk = it*16 + krow;
        float4 f = *(const float4*)(W + (size_t)(k0+kk)*N + n0 + col4);
        tile[kk][col4+0] = f.x; tile[kk][col4+1] = f.y;
        tile[kk][col4+2] = f.z; tile[kk][col4+3] = f.w;
    }
    __syncthreads();
    int n = t >> 2, ch = t & 3;
    ushort o[16];
#pragma unroll
    for (int i = 0; i < 16; ++i) o[i] = f2b(tile[ch*16 + i][n]);
    uint4* dst = (uint4*)(WT + (size_t)(n0+n)*K + k0 + ch*16);
    dst[0] = ((const uint4*)o)[0];
    dst[1] = ((const uint4*)o)[1];
}

// ---------------------------------------------------------------------------
// bf16 MFMA GEMM: C[M,N] = A[M,K] * Bt[N,K]^T, 128x128 tile, BK=32
// Grid: blockIdx.x = m-tile (fastest -> co-resident blocks share the B-tile,
//       keeping WT L2/L3-hot), blockIdx.y = n-tile, blockIdx.z = K-split.
// EPI=0: C = acc + bias[n] -> bf16 Cb, via per-wave LDS transpose + uint4
// EPI=1: fp32 split-K partial tile -> Out + z*M*N, coalesced scalar f32
// ---------------------------------------------------------------------------
template <int EPI>
__global__ __launch_bounds__(256, 2) void gemm_bt(
    const ushort* __restrict__ A, const ushort* __restrict__ Bt,
    const float* __restrict__ bias, ushort* __restrict__ Cb,
    float* __restrict__ Out, int M, int N, int K, int KS) {
    __shared__ __align__(16) ushort sA[128*32];
    __shared__ __align__(16) ushort sB[128*32];
    const int tid = threadIdx.x;
    const int wave = tid >> 6, lane = tid & 63;
    const int lrow = lane & 15, lquad = lane >> 4;
    const int m0 = blockIdx.x * 128, n0 = blockIdx.y * 128;
    const int wm = (wave & 1) * 64, wn = (wave >> 1) * 64;

    // staging map: chunk ci -> LDS pos (r, q'); global kquad = q' ^ ((r>>1)&3)
    const int r0 = tid >> 2,        q0 = (tid & 3) ^ ((r0 >> 1) & 3);
    const int r1 = (256+tid) >> 2,  q1 = (tid & 3) ^ ((r1 >> 1) & 3);
    ushort* lA0 = sA + wave*512;          ushort* lA1 = sA + 2048 + wave*512;
    ushort* lB0 = sB + wave*512;          ushort* lB1 = sB + 2048 + wave*512;
    const size_t aRow0 = (size_t)(m0 + r0) * K, aRow1 = (size_t)(m0 + r1) * K;
    const size_t bRow0 = (size_t)(n0 + r0) * K, bRow1 = (size_t)(n0 + r1) * K;

    // fragment LDS addresses (constant per thread)
    const ushort* aAddr[4]; const ushort* bAddr[4];
#pragma unroll
    for (int i = 0; i < 4; ++i) {
        int r = wm + i*16 + lrow;
        aAddr[i] = sA + r*32 + ((lquad ^ ((r >> 1) & 3)) * 8);
        int nn = wn + i*16 + lrow;
        bAddr[i] = sB + nn*32 + ((lquad ^ ((nn >> 1) & 3)) * 8);
    }

    f32x4 acc[4][4];
#pragma unroll
    for (int i = 0; i < 4; ++i)
#pragma unroll
        for (int j = 0; j < 4; ++j) acc[i][j] = f32x4{0.f, 0.f, 0.f, 0.f};

    const int kbeg = (EPI == 1) ? blockIdx.z * KS : 0;
    const int kend = kbeg + KS;
    for (int kt = kbeg; kt < kend; kt += 32) {
        __syncthreads();
        g2l16(A  + aRow0 + kt + q0*8, lA0);
        g2l16(A  + aRow1 + kt + q1*8, lA1);
        g2l16(Bt + bRow0 + kt + q0*8, lB0);
        g2l16(Bt + bRow1 + kt + q1*8, lB1);
        __syncthreads();
        bf16x8 af[4], bg[4];
#pragma unroll
        for (int i = 0; i < 4; ++i) {
            af[i] = __builtin_bit_cast(bf16x8, *(const uint4*)aAddr[i]);
            bg[i] = __builtin_bit_cast(bf16x8, *(const uint4*)bAddr[i]);
        }
#pragma unroll
        for (int i = 0; i < 4; ++i)
#pragma unroll
            for (int j = 0; j < 4; ++j)
                acc[i][j] = __builtin_amdgcn_mfma_f32_16x16x32_bf16(
                    af[i], bg[j], acc[i][j], 0, 0, 0);
    }

    if constexpr (EPI == 0) {
        // bias per j-column
        float bvj[4];
#pragma unroll
        for (int j = 0; j < 4; ++j) bvj[j] = bias[n0 + wn + j*16 + lrow];
        __syncthreads();                    // all waves done reading sA/sB
        ushort* warena = sA + wave * 2048;  // 4 KB per wave: 32 rows x 64 cols
#pragma unroll
        for (int pass = 0; pass < 2; ++pass) {
#pragma unroll
            for (int ih = 0; ih < 2; ++ih) {
                const int i = pass*2 + ih;
#pragma unroll
                for (int j = 0; j < 4; ++j)
#pragma unroll
                    for (int re = 0; re < 4; ++re) {
                        int mrow = ih*16 + lquad*4 + re;     // 0..31
                        int col  = j*16 + lrow;              // 0..63
                        warena[mrow*64 + col] = f2b(acc[i][j][re] + bvj[j]);
                    }
            }
            // intra-wave only (lockstep) -> no barrier needed
#pragma unroll
            for (int t2 = 0; t2 < 4; ++t2) {
                int chunk = t2*64 + lane;          // 0..255
                int row = chunk >> 3, seg = chunk & 7;
                uint4 v = *(const uint4*)&warena[row*64 + seg*8];
                *(uint4*)&Cb[(size_t)(m0 + wm + pass*32 + row)*N
                             + n0 + wn + seg*8] = v;
            }
        }
    } else {
        float* P = Out + (size_t)blockIdx.z * M * N;
#pragma unroll
        for (int j = 0; j < 4; ++j) {
            int n = n0 + wn + j*16 + lrow;
#pragma unroll
            for (int i = 0; i < 4; ++i) {
                int mbase = m0 + wm + i*16 + lquad*4;
#pragma unroll
                for (int re = 0; re < 4; ++re)
                    P[(size_t)(mbase + re)*N + n] = acc[i][j][re];
            }
        }
    }
}

// ---------------------------------------------------------------------------
// Per-patch: 8x8 circular conv (q ⊛ k), LN2 over c, gate by v, pack A2 rows.
// One block per patch; thread t -> (head = t>>5, c = t&31). A2 aliases Qb
// (each row fully consumed into regs before overwrite).
// R3 fix: only q[64] in VGPRs; K streamed from LDS (transposed, lane-
// consecutive -> conflict-free); LN2 butterfly batched 8-wide; V gating via
// scattered global u16 loads (prefetched across the 512-FMA nest).
// VGPR target <=170 (3 waves/SIMD); LDS 33 KB single buffer.
// ---------------------------------------------------------------------------
__global__ __launch_bounds__(256, 3) void conv_gate(
    const ushort* __restrict__ Qb, const ushort* __restrict__ Kb,
    const ushort* __restrict__ Vb, const float* __restrict__ ln2_s,
    const float* __restrict__ ln2_b, ushort* __restrict__ A2) {
    __shared__ ushort sT[64 * 258];                // 33 KB, [p or a][h*32+c]
    const int t = threadIdx.x;
    const int m = blockIdx.x;
    const int c = t & 31, h = t >> 5;
    const ushort* Qrow = Qb + (size_t)m * 16384;
    const ushort* Krow = Kb + (size_t)m * 16384;
    const ushort* Vrow = Vb + (size_t)m * 16384;

    // stage transposed: global f = cc*512 + p*8 + head  ->  sT[p*258+head*32+cc]
    // (within a wave: p = lane, cc const -> dword addr = lane*129+const,
    //  lane-distinct mod 32 -> conflict-free)
#define STAGE_T(SRC)                                                        \
    {                                                                       \
        _Pragma("unroll")                                                   \
        for (int it = 0; it < 8; ++it) {                                    \
            int ci = it*256 + t;                                            \
            int p = ci & 63, cc = ci >> 6;                                  \
            uint4 w = ((const uint4*)(SRC))[ci];                            \
            uint uu[4] = {w.x, w.y, w.z, w.w};                              \
            _Pragma("unroll")                                               \
            for (int e = 0; e < 4; ++e) {                                   \
                sT[p*258 + (2*e  )*32 + cc] = (ushort)(uu[e] & 0xffffu);    \
                sT[p*258 + (2*e+1)*32 + cc] = (ushort)(uu[e] >> 16);        \
            }                                                               \
        }                                                                   \
    }

    float q[64];
    STAGE_T(Qrow);
    __syncthreads();
#pragma unroll
    for (int p = 0; p < 64; ++p) q[p] = b2f(sT[p*258 + t]);
    __syncthreads();
    STAGE_T(Krow);     // K stays in LDS for the conv loop
    __syncthreads();
#undef STAGE_T

    const float scl = ln2_s[c], bia = ln2_b[c];
    ushort* A2row = A2 + (size_t)m * 16384;
    const ushort* vbase = Vrow + c*512 + h;        // + p0*64 + p1*8

#pragma unroll
    for (int p0 = 0; p0 < 8; ++p0) {
        // prefetch V octet (consumed after the FMA nest -> latency hidden)
        ushort vraw[8];
#pragma unroll
        for (int p1 = 0; p1 < 8; ++p1) vraw[p1] = vbase[p0*64 + p1*8];

        float o[8];
#pragma unroll
        for (int p1 = 0; p1 < 8; ++p1) o[p1] = 0.f;
#pragma unroll
        for (int b0 = 0; b0 < 8; ++b0) {
            const int qr = ((p0 - b0) & 7) * 8;
#pragma unroll
            for (int b1 = 0; b1 < 8; ++b1) {
                float kv = b2f(sT[(b0*8 + b1)*258 + t]);
#pragma unroll
                for (int p1 = 0; p1 < 8; ++p1)
                    o[p1] += kv * q[qr + ((p1 - b1) & 7)];
            }
        }

        // batched LN2 butterfly over the 32 channels (lanes grouped by 32)
        float s1[8], s2[8];
#pragma unroll
        for (int p1 = 0; p1 < 8; ++p1) { s1[p1] = o[p1]; s2[p1] = o[p1]*o[p1]; }
#pragma unroll
        for (int mask = 1; mask <= 16; mask <<= 1) {
#pragma unroll
            for (int p1 = 0; p1 < 8; ++p1) {
                s1[p1] += __shfl_xor(s1[p1], mask, 64);
                s2[p1] += __shfl_xor(s2[p1], mask, 64);
            }
        }
#pragma unroll
        for (int p1 = 0; p1 < 8; ++p1) {
            float mu  = s1[p1] * 0.03125f;
            float var = s2[p1] * 0.03125f - mu * mu;
            float inv = rsqrtf(var + 1e-6f);
            float on  = (o[p1] - mu) * inv * scl + bia;
            A2row[(p0*8 + p1)*256 + t] = f2b(b2f(vraw[p1]) * on);
        }
    }
}

// ---------------------------------------------------------------------------
// reduce_out: out[pix] = x[pix] + bo[n] + sum_z P[z][m][n], patch->pixel remap
// One block per patch m. P rows read coalesced; out written coalesced.
// ---------------------------------------------------------------------------
__global__ __launch_bounds__(256) void reduce_out(
    const float* __restrict__ Pp, const float* __restrict__ x,
    const float* __restrict__ bo, float* __restrict__ out) {
    __shared__ float sn[32*65];                    // padded [c][64]
    const int t = threadIdx.x, m = blockIdx.x;
    float4 s0 = {0.f,0.f,0.f,0.f}, s1 = {0.f,0.f,0.f,0.f};
#pragma unroll
    for (int z = 0; z < 4; ++z) {
        const float4* base =
            (const float4*)(Pp + ((size_t)z*2048 + m) * 2048);
        float4 u = base[t], v = base[256 + t];
        s0.x += u.x; s0.y += u.y; s0.z += u.z; s0.w += u.w;
        s1.x += v.x; s1.y += v.y; s1.z += v.z; s1.w += v.w;
    }
    {
        int na = t*4;                              // chunk t   -> n = 4t
        int nb = (256 + t)*4;                      // chunk 256+t
        float va[4] = {s0.x, s0.y, s0.z, s0.w};
        float vb[4] = {s1.x, s1.y, s1.z, s1.w};
#pragma unroll
        for (int e = 0; e < 4; ++e) {
            int n1 = na + e, n2 = nb + e;
            sn[(n1 >> 6)*65 + (n1 & 63)] = va[e];
            sn[(n2 >> 6)*65 + (n2 & 63)] = vb[e];
        }
    }
    __syncthreads();
    const int c = t & 31, pi = t >> 5;
    const int bb = m >> 10, gh = (m >> 5) & 31, gw = m & 31;
#pragma unroll
    for (int it = 0; it < 8; ++it) {
        int p = it*8 + pi;                         // 0..63
        int p0 = p >> 3, p1 = p & 7;
        int n = c*64 + p;
        size_t oi = ((size_t)((bb*256 + gh*8 + p0)*256 + gw*8 + p1))*32 + c;
        out[oi] = x[oi] + bo[n] + sn[c*65 + p];
    }
}

// ---------------------------------------------------------------------------
extern "C" void kernel_launch(void* const* d_in, const int* in_sizes, int n_in,
                              void* d_out, int out_size, void* d_ws, size_t ws_size,
                              hipStream_t stream) {
    (void)in_sizes; (void)n_in; (void)out_size; (void)ws_size;
    const float* x    = (const float*)d_in[0];
    const float* ln1s = (const float*)d_in[1];
    const float* ln1b = (const float*)d_in[2];
    const float* Wq   = (const float*)d_in[3];
    const float* bq   = (const float*)d_in[4];
    const float* Wk   = (const float*)d_in[5];
    const float* bk   = (const float*)d_in[6];
    const float* Wv   = (const float*)d_in[7];
    const float* bv   = (const float*)d_in[8];
    const float* ln2s = (const float*)d_in[9];
    const float* ln2b = (const float*)d_in[10];
    const float* Wo   = (const float*)d_in[11];
    const float* bo   = (const float*)d_in[12];
    float* out = (float*)d_out;

    char* ws = (char*)d_ws;
    ushort* A1 = (ushort*)(ws);                      //  8.0 MB  [2048,2048] bf16
    ushort* WT = (ushort*)(ws + 8388608);            // 64.0 MB  [N,K] bf16
    ushort* Qb = (ushort*)(ws + 75497472);           // 64.0 MB  [2048,16384] bf16
    ushort* Kb = (ushort*)(ws + 142606336);          // 64.0 MB
    ushort* Vb = (ushort*)(ws + 209715200);          // 64.0 MB  (end 276.8 MB)
    ushort* A2 = Qb;                                 // aliases Qb (safe: per-row)
    float*  Pp = (float*)Kb;                         // 64.0 MB split-K partials
                                                     // (Kb dead after conv_gate)

    ln1_pack<<<512, 256, 0, stream>>>(x, ln1s, ln1b, A1);

    wcvt<<<dim3(256, 32), 256, 0, stream>>>(Wq, WT, 2048, 16384);
    gemm_bt<0><<<dim3(16, 128), 256, 0, stream>>>(A1, WT, bq, Qb, nullptr,
                                                  2048, 16384, 2048, 2048);
    wcvt<<<dim3(256, 32), 256, 0, stream>>>(Wk, WT, 2048, 16384);
    gemm_bt<0><<<dim3(16, 128), 256, 0, stream>>>(A1, WT, bk, Kb, nullptr,
                                                  2048, 16384, 2048, 2048);
    wcvt<<<dim3(256, 32), 256, 0, stream>>>(Wv, WT, 2048, 16384);
    gemm_bt<0><<<dim3(16, 128), 256, 0, stream>>>(A1, WT, bv, Vb, nullptr,
                                                  2048, 16384, 2048, 2048);

    conv_gate<<<2048, 256, 0, stream>>>(Qb, Kb, Vb, ln2s, ln2b, A2);

    wcvt<<<dim3(32, 256), 256, 0, stream>>>(Wo, WT, 16384, 2048);
    gemm_bt<1><<<dim3(16, 16, 4), 256, 0, stream>>>(A2, WT, nullptr, nullptr, Pp,
                                                    2048, 2048, 16384, 4096);
    reduce_out<<<2048, 256, 0, stream>>>(Pp, x, bo, out);
}